// Round 1
// baseline (9438.110 us; speedup 1.0000x reference)
//
#include <hip/hip_runtime.h>
#include <hip/hip_bf16.h>

// Problem constants (EntropyByteLatentTransformer)
#define D_MODEL 512
#define NHEAD   8
#define DHEAD   64
#define SEQ     1024
#define NBATCH  8
#define NTOK    (NBATCH * SEQ)   // 8192
#define DFF_N   2048
#define NLAYER  8
#define VOCAB   258

__device__ __forceinline__ float gelu_f(float x) {
    return 0.5f * x * (1.0f + erff(x * 0.70710678118654752f));
}

// ---------------- entropy features + embedding ----------------
// h[t, d] = embed[x[t]][d] + ent(t) * ep_w[d] + ep_b[d]
__global__ __launch_bounds__(128) void embed_kernel(
    const int* __restrict__ x, const float* __restrict__ embed,
    const float* __restrict__ ep_w, const float* __restrict__ ep_b,
    float* __restrict__ h)
{
    int t = blockIdx.x;            // 0..NTOK-1
    int pos = t & (SEQ - 1);
    float ent = 0.0f;
    if (pos <= SEQ - 8) {
        int v[8];
        #pragma unroll
        for (int i = 0; i < 8; i++) v[i] = x[t + i];
        float s = 0.0f;
        #pragma unroll
        for (int i = 0; i < 8; i++) {
            int c = 0;
            #pragma unroll
            for (int j = 0; j < 8; j++) c += (v[j] == v[i]) ? 1 : 0;
            s += log2f((float)c);
        }
        // -sum_v p log2 p  ==  3 - (1/8) sum_i log2(c_i)
        ent = 3.0f - 0.125f * s;
    }
    int tok = x[t];
    int d = threadIdx.x << 2;
    float e[4], w[4], bb[4], r[4];
    *(float4*)e  = *(const float4*)(embed + (size_t)tok * D_MODEL + d);
    *(float4*)w  = *(const float4*)(ep_w + d);
    *(float4*)bb = *(const float4*)(ep_b + d);
    #pragma unroll
    for (int j = 0; j < 4; j++) r[j] = e[j] + ent * w[j] + bb[j];
    *(float4*)(h + (size_t)t * D_MODEL + d) = *(float4*)r;
}

// ---------------- LayerNorm (one wave per token row of 512) ----------------
__global__ __launch_bounds__(256) void ln_kernel(
    const float* __restrict__ in, const float* __restrict__ w,
    const float* __restrict__ b, float* __restrict__ out)
{
    int wid = threadIdx.x >> 6, lane = threadIdx.x & 63;
    int t = (blockIdx.x << 2) + wid;
    const float* row = in + (size_t)t * D_MODEL;
    float a[8];
    *(float4*)(a)     = *(const float4*)(row + (lane << 2));
    *(float4*)(a + 4) = *(const float4*)(row + 256 + (lane << 2));
    float s = 0.f;
    #pragma unroll
    for (int j = 0; j < 8; j++) s += a[j];
    #pragma unroll
    for (int o = 1; o < 64; o <<= 1) s += __shfl_xor(s, o);
    float mu = s * (1.0f / 512.0f);
    float vs = 0.f;
    #pragma unroll
    for (int j = 0; j < 8; j++) { float d0 = a[j] - mu; vs += d0 * d0; }
    #pragma unroll
    for (int o = 1; o < 64; o <<= 1) vs += __shfl_xor(vs, o);
    float inv = rsqrtf(vs * (1.0f / 512.0f) + 1e-5f);
    float ww[8], bbv[8], r[8];
    *(float4*)(ww)      = *(const float4*)(w + (lane << 2));
    *(float4*)(ww + 4)  = *(const float4*)(w + 256 + (lane << 2));
    *(float4*)(bbv)     = *(const float4*)(b + (lane << 2));
    *(float4*)(bbv + 4) = *(const float4*)(b + 256 + (lane << 2));
    #pragma unroll
    for (int j = 0; j < 8; j++) r[j] = (a[j] - mu) * inv * ww[j] + bbv[j];
    float* orow = out + (size_t)t * D_MODEL;
    *(float4*)(orow + (lane << 2))       = *(float4*)(r);
    *(float4*)(orow + 256 + (lane << 2)) = *(float4*)(r + 4);
}

// ---------------- f32 GEMM: C[M,N] = A[M,K] @ B[N,K]^T (+bias)(+gelu/resid) -------
// fuse: 0 = none, 1 = gelu, 2 = add resid
__global__ __launch_bounds__(256) void gemm_kernel(
    const float* __restrict__ A, const float* __restrict__ Bm,
    const float* __restrict__ bias, const float* __restrict__ resid,
    float* __restrict__ C, int M, int N, int K, int fuse)
{
    __shared__ float As[32][68];   // [k][m]
    __shared__ float Bs[32][68];   // [k][n]
    int tid = threadIdx.x;
    int tx = tid & 15, ty = tid >> 4;
    int m0 = blockIdx.x << 6, n0 = blockIdx.y << 6;
    float acc[4][4] = {{0.f}};
    int nk = K >> 5;
    for (int kt = 0; kt < nk; kt++) {
        int k0 = kt << 5;
        __syncthreads();
        #pragma unroll
        for (int i = 0; i < 2; i++) {
            int f = tid + i * 256;            // 0..511
            int r = f >> 3, c4 = (f & 7) << 2;
            float va[4];
            *(float4*)va = *(const float4*)(A + (size_t)(m0 + r) * K + k0 + c4);
            As[c4 + 0][r] = va[0]; As[c4 + 1][r] = va[1];
            As[c4 + 2][r] = va[2]; As[c4 + 3][r] = va[3];
            int n = n0 + r;
            float vb[4] = {0.f, 0.f, 0.f, 0.f};
            if (n < N) *(float4*)vb = *(const float4*)(Bm + (size_t)n * K + k0 + c4);
            Bs[c4 + 0][r] = vb[0]; Bs[c4 + 1][r] = vb[1];
            Bs[c4 + 2][r] = vb[2]; Bs[c4 + 3][r] = vb[3];
        }
        __syncthreads();
        #pragma unroll
        for (int k = 0; k < 32; k++) {
            float a4[4], b4[4];
            *(float4*)a4 = *(const float4*)&As[k][ty << 2];
            *(float4*)b4 = *(const float4*)&Bs[k][tx << 2];
            #pragma unroll
            for (int i = 0; i < 4; i++)
                #pragma unroll
                for (int j = 0; j < 4; j++)
                    acc[i][j] += a4[i] * b4[j];
        }
    }
    int rowb = m0 + (ty << 2), colb = n0 + (tx << 2);
    #pragma unroll
    for (int i = 0; i < 4; i++) {
        int row = rowb + i;
        float v[4];
        #pragma unroll
        for (int j = 0; j < 4; j++) v[j] = acc[i][j];
        if (bias) {
            #pragma unroll
            for (int j = 0; j < 4; j++) v[j] += bias[colb + j];
        }
        if (fuse == 1) {
            #pragma unroll
            for (int j = 0; j < 4; j++) v[j] = gelu_f(v[j]);
        } else if (fuse == 2) {
            float rr[4];
            *(float4*)rr = *(const float4*)(resid + (size_t)row * N + colb);
            #pragma unroll
            for (int j = 0; j < 4; j++) v[j] += rr[j];
        }
        float* cp = C + (size_t)row * N + colb;
        if (((N & 3) == 0) && (colb + 3 < N)) {
            *(float4*)cp = *(float4*)v;
        } else {
            #pragma unroll
            for (int j = 0; j < 4; j++)
                if (colb + j < N) cp[j] = v[j];
        }
    }
}

// ---------------- flash-style attention (full, non-causal) ----------------
// qkv: [NTOK, 1536] (q | k | v, each D=512, head h at cols h*64..)
// out: [NTOK, 512]
__global__ __launch_bounds__(256) void attn_kernel(
    const float* __restrict__ qkv, float* __restrict__ out)
{
    __shared__ float Qs[64][68];    // [row][d], pre-scaled by 1/8
    __shared__ float Kst[64][68];   // [d][m]   (transposed)
    __shared__ float Vs[64][68];    // [m][d]
    __shared__ float Ps[64][68];    // [row][m]
    int tid = threadIdx.x;
    int tx = tid & 15, ty = tid >> 4;
    int bh = blockIdx.y; int b = bh >> 3, hh = bh & 7;
    int q0 = blockIdx.x << 6;
    const float* base = qkv + (size_t)b * SEQ * 1536 + hh * DHEAD;

    #pragma unroll
    for (int i = 0; i < 4; i++) {
        int f = tid + i * 256;               // 0..1023
        int r = f >> 4, c4 = (f & 15) << 2;
        float v[4];
        *(float4*)v = *(const float4*)(base + (size_t)(q0 + r) * 1536 + c4);
        #pragma unroll
        for (int j = 0; j < 4; j++) v[j] *= 0.125f;
        *(float4*)&Qs[r][c4] = *(float4*)v;
    }

    float accO[4][4] = {{0.f}};
    float m_run[4], l_run[4];
    #pragma unroll
    for (int i = 0; i < 4; i++) { m_run[i] = -1e30f; l_run[i] = 0.f; }

    for (int kt = 0; kt < SEQ / 64; kt++) {
        int mk = kt << 6;
        __syncthreads();   // protect Kst/Vs/Ps from previous iteration readers
        #pragma unroll
        for (int i = 0; i < 4; i++) {
            int f = tid + i * 256;
            int r = f >> 4, c4 = (f & 15) << 2;
            float kv[4], vv[4];
            *(float4*)kv = *(const float4*)(base + 512 + (size_t)(mk + r) * 1536 + c4);
            Kst[c4 + 0][r] = kv[0]; Kst[c4 + 1][r] = kv[1];
            Kst[c4 + 2][r] = kv[2]; Kst[c4 + 3][r] = kv[3];
            *(float4*)vv = *(const float4*)(base + 1024 + (size_t)(mk + r) * 1536 + c4);
            *(float4*)&Vs[r][c4] = *(float4*)vv;
        }
        __syncthreads();

        // S tile: s[i][j] = sum_d Qs[ty*4+i][d] * K[tx*4+j][d]
        float s[4][4] = {{0.f}};
        #pragma unroll
        for (int d4 = 0; d4 < 16; d4++) {
            float q4[4][4], k4[4][4];
            #pragma unroll
            for (int i = 0; i < 4; i++)
                *(float4*)q4[i] = *(const float4*)&Qs[(ty << 2) + i][d4 << 2];
            #pragma unroll
            for (int dd = 0; dd < 4; dd++)
                *(float4*)k4[dd] = *(const float4*)&Kst[(d4 << 2) + dd][tx << 2];
            #pragma unroll
            for (int i = 0; i < 4; i++)
                #pragma unroll
                for (int dd = 0; dd < 4; dd++)
                    #pragma unroll
                    for (int j = 0; j < 4; j++)
                        s[i][j] += q4[i][dd] * k4[dd][j];
        }

        // online softmax (rows split across 16 lanes sharing same ty)
        #pragma unroll
        for (int i = 0; i < 4; i++) {
            float mt = fmaxf(fmaxf(s[i][0], s[i][1]), fmaxf(s[i][2], s[i][3]));
            #pragma unroll
            for (int o = 1; o < 16; o <<= 1) mt = fmaxf(mt, __shfl_xor(mt, o));
            float mn = fmaxf(m_run[i], mt);
            float sc = expf(m_run[i] - mn);
            float p[4], rs = 0.f;
            #pragma unroll
            for (int j = 0; j < 4; j++) { p[j] = expf(s[i][j] - mn); rs += p[j]; }
            #pragma unroll
            for (int o = 1; o < 16; o <<= 1) rs += __shfl_xor(rs, o);
            l_run[i] = l_run[i] * sc + rs;
            m_run[i] = mn;
            #pragma unroll
            for (int j = 0; j < 4; j++) { accO[i][j] *= sc; s[i][j] = p[j]; }
        }
        // write P tile
        #pragma unroll
        for (int i = 0; i < 4; i++)
            *(float4*)&Ps[(ty << 2) + i][tx << 2] = *(float4*)s[i];
        __syncthreads();

        // O += P @ V
        #pragma unroll
        for (int m4 = 0; m4 < 16; m4++) {
            float p4[4][4], v4[4][4];
            #pragma unroll
            for (int i = 0; i < 4; i++)
                *(float4*)p4[i] = *(const float4*)&Ps[(ty << 2) + i][m4 << 2];
            #pragma unroll
            for (int mm = 0; mm < 4; mm++)
                *(float4*)v4[mm] = *(const float4*)&Vs[(m4 << 2) + mm][tx << 2];
            #pragma unroll
            for (int i = 0; i < 4; i++)
                #pragma unroll
                for (int mm = 0; mm < 4; mm++)
                    #pragma unroll
                    for (int j = 0; j < 4; j++)
                        accO[i][j] += p4[i][mm] * v4[mm][j];
        }
    }

    #pragma unroll
    for (int i = 0; i < 4; i++) {
        float inv = 1.0f / l_run[i];
        float o4[4];
        #pragma unroll
        for (int j = 0; j < 4; j++) o4[j] = accO[i][j] * inv;
        int row = q0 + (ty << 2) + i;
        *(float4*)(out + ((size_t)(b * SEQ + row)) * D_MODEL + hh * DHEAD + (tx << 2))
            = *(float4*)o4;
    }
}

extern "C" void kernel_launch(void* const* d_in, const int* in_sizes, int n_in,
                              void* d_out, int out_size, void* d_ws, size_t ws_size,
                              hipStream_t stream) {
    const int*   x     = (const int*)  d_in[0];
    const float* embed = (const float*)d_in[1];
    const float* ep_w  = (const float*)d_in[2];
    const float* ep_b  = (const float*)d_in[3];
    const float* in_w  = (const float*)d_in[4];
    const float* in_b  = (const float*)d_in[5];
    const float* op_w  = (const float*)d_in[6];
    const float* op_b  = (const float*)d_in[7];
    const float* ln1_w = (const float*)d_in[8];
    const float* ln1_b = (const float*)d_in[9];
    const float* ln2_w = (const float*)d_in[10];
    const float* ln2_b = (const float*)d_in[11];
    const float* f1_w  = (const float*)d_in[12];
    const float* f1_b  = (const float*)d_in[13];
    const float* f2_w  = (const float*)d_in[14];
    const float* f2_b  = (const float*)d_in[15];
    const float* out_w = (const float*)d_in[16];
    float* out = (float*)d_out;

    // workspace: h [8192,512] | g [8192,512] | big [8192,2048]  (~100.7 MB)
    char* ws = (char*)d_ws;
    float* h   = (float*)(ws);
    float* g   = (float*)(ws + (size_t)NTOK * D_MODEL * 4);
    float* big = (float*)(ws + (size_t)2 * NTOK * D_MODEL * 4);

    embed_kernel<<<NTOK, 128, 0, stream>>>(x, embed, ep_w, ep_b, h);

    for (int l = 0; l < NLAYER; l++) {
        ln_kernel<<<NTOK / 4, 256, 0, stream>>>(h, ln1_w + l * D_MODEL, ln1_b + l * D_MODEL, g);
        gemm_kernel<<<dim3(NTOK / 64, 1536 / 64), 256, 0, stream>>>(
            g, in_w + (size_t)l * 1536 * D_MODEL, in_b + l * 1536, nullptr, big,
            NTOK, 1536, 512, 0);
        attn_kernel<<<dim3(SEQ / 64, NBATCH * NHEAD), 256, 0, stream>>>(big, g);
        gemm_kernel<<<dim3(NTOK / 64, 512 / 64), 256, 0, stream>>>(
            g, op_w + (size_t)l * D_MODEL * D_MODEL, op_b + l * D_MODEL, h, h,
            NTOK, 512, 512, 2);
        ln_kernel<<<NTOK / 4, 256, 0, stream>>>(h, ln2_w + l * D_MODEL, ln2_b + l * D_MODEL, g);
        gemm_kernel<<<dim3(NTOK / 64, DFF_N / 64), 256, 0, stream>>>(
            g, f1_w + (size_t)l * DFF_N * D_MODEL, f1_b + l * DFF_N, nullptr, big,
            NTOK, DFF_N, 512, 1);
        gemm_kernel<<<dim3(NTOK / 64, 512 / 64), 256, 0, stream>>>(
            big, f2_w + (size_t)l * D_MODEL * DFF_N, f2_b + l * D_MODEL, h, h,
            NTOK, 512, DFF_N, 2);
    }

    gemm_kernel<<<dim3(NTOK / 64, (VOCAB + 63) / 64), 256, 0, stream>>>(
        h, out_w, nullptr, nullptr, out, NTOK, VOCAB, 512, 0);
}

// Round 3
// 2138.868 us; speedup vs baseline: 4.4127x; 4.4127x over previous
//
#include <hip/hip_runtime.h>
#include <hip/hip_bf16.h>

#define D_MODEL 512
#define NHEAD   8
#define DHEAD   64
#define SEQ     1024
#define NBATCH  8
#define NTOK    8192
#define DFF_N   2048
#define NLAYER  8
#define VOCAB   258
#define VPAD    384

typedef float f32x4 __attribute__((ext_vector_type(4)));
typedef short s16x8 __attribute__((ext_vector_type(8)));

__device__ __forceinline__ ushort f2b(float f) {
    union { float f; unsigned u; } v; v.f = f;
    unsigned r = (v.u + 0x7fffu + ((v.u >> 16) & 1u)) >> 16;
    return (ushort)r;
}
__device__ __forceinline__ float gelu_f(float x) {
    return 0.5f * x * (1.0f + erff(x * 0.70710678118654752f));
}
__device__ __forceinline__ void gl_lds16(const void* g, void* l) {
    __builtin_amdgcn_global_load_lds(
        (const __attribute__((address_space(1))) void*)g,
        (__attribute__((address_space(3))) void*)l, 16, 0, 0);
}

// ---------------- f32 -> bf16 convert ----------------
__global__ __launch_bounds__(256) void cvt_bf16(
    const float* __restrict__ in, ushort* __restrict__ out, int n)
{
    int i = (blockIdx.x * 256 + threadIdx.x) << 2;
    if (i >= n) return;
    float4 v = *(const float4*)(in + i);
    ushort4 o;
    o.x = f2b(v.x); o.y = f2b(v.y); o.z = f2b(v.z); o.w = f2b(v.w);
    *(ushort4*)(out + i) = o;
}

// ---------------- entropy features + embedding (f32 out) ----------------
__global__ __launch_bounds__(128) void embed_kernel(
    const int* __restrict__ x, const float* __restrict__ embed,
    const float* __restrict__ ep_w, const float* __restrict__ ep_b,
    float* __restrict__ h)
{
    int t = blockIdx.x;
    int pos = t & (SEQ - 1);
    float ent = 0.0f;
    if (pos <= SEQ - 8) {
        int v[8];
        #pragma unroll
        for (int i = 0; i < 8; i++) v[i] = x[t + i];
        float s = 0.0f;
        #pragma unroll
        for (int i = 0; i < 8; i++) {
            int c = 0;
            #pragma unroll
            for (int j = 0; j < 8; j++) c += (v[j] == v[i]) ? 1 : 0;
            s += log2f((float)c);
        }
        ent = 3.0f - 0.125f * s;
    }
    int tok = x[t];
    int d = threadIdx.x << 2;
    float e[4], w[4], bb[4], r[4];
    *(float4*)e  = *(const float4*)(embed + (size_t)tok * D_MODEL + d);
    *(float4*)w  = *(const float4*)(ep_w + d);
    *(float4*)bb = *(const float4*)(ep_b + d);
    #pragma unroll
    for (int j = 0; j < 4; j++) r[j] = e[j] + ent * w[j] + bb[j];
    *(float4*)(h + (size_t)t * D_MODEL + d) = *(float4*)r;
}

// ---------------- LayerNorm: f32 in -> bf16 out ----------------
__global__ __launch_bounds__(256) void ln_kernel(
    const float* __restrict__ in, const float* __restrict__ w,
    const float* __restrict__ b, ushort* __restrict__ out)
{
    int wid = threadIdx.x >> 6, lane = threadIdx.x & 63;
    int t = (blockIdx.x << 2) + wid;
    const float* row = in + (size_t)t * D_MODEL;
    float a[8];
    *(float4*)(a)     = *(const float4*)(row + (lane << 2));
    *(float4*)(a + 4) = *(const float4*)(row + 256 + (lane << 2));
    float s = 0.f;
    #pragma unroll
    for (int j = 0; j < 8; j++) s += a[j];
    #pragma unroll
    for (int o = 1; o < 64; o <<= 1) s += __shfl_xor(s, o);
    float mu = s * (1.0f / 512.0f);
    float vs = 0.f;
    #pragma unroll
    for (int j = 0; j < 8; j++) { float d0 = a[j] - mu; vs += d0 * d0; }
    #pragma unroll
    for (int o = 1; o < 64; o <<= 1) vs += __shfl_xor(vs, o);
    float inv = rsqrtf(vs * (1.0f / 512.0f) + 1e-5f);
    float ww[8], bbv[8];
    *(float4*)(ww)      = *(const float4*)(w + (lane << 2));
    *(float4*)(ww + 4)  = *(const float4*)(w + 256 + (lane << 2));
    *(float4*)(bbv)     = *(const float4*)(b + (lane << 2));
    *(float4*)(bbv + 4) = *(const float4*)(b + 256 + (lane << 2));
    ushort* orow = out + (size_t)t * D_MODEL;
    ushort4 o1, o2;
    o1.x = f2b((a[0] - mu) * inv * ww[0] + bbv[0]);
    o1.y = f2b((a[1] - mu) * inv * ww[1] + bbv[1]);
    o1.z = f2b((a[2] - mu) * inv * ww[2] + bbv[2]);
    o1.w = f2b((a[3] - mu) * inv * ww[3] + bbv[3]);
    o2.x = f2b((a[4] - mu) * inv * ww[4] + bbv[4]);
    o2.y = f2b((a[5] - mu) * inv * ww[5] + bbv[5]);
    o2.z = f2b((a[6] - mu) * inv * ww[6] + bbv[6]);
    o2.w = f2b((a[7] - mu) * inv * ww[7] + bbv[7]);
    *(ushort4*)(orow + (lane << 2))       = o1;
    *(ushort4*)(orow + 256 + (lane << 2)) = o2;
}

// ---------------- bf16 MFMA GEMM: C[M,N] = A[M,K] @ B[N,K]^T ----------------
// m97 structure: 128x128 tile, BK=32, 4 waves (2x2), global_load_lds staging.
// fuse: 0 none, 1 gelu, 2 +resid. Cf (f32) and/or Cb (bf16) outputs.
__global__ __launch_bounds__(256) void gemm_bf16(
    const ushort* __restrict__ A, const ushort* __restrict__ Bw,
    const float* __restrict__ bias, const float* __restrict__ resid,
    float* __restrict__ Cf, ushort* __restrict__ Cb,
    int M, int N, int K, int fuse)
{
    __shared__ ushort As[128 * 32];
    __shared__ ushort Bs[128 * 32];
    const int tid = threadIdx.x;
    const int l = tid & 63, w = tid >> 6;
    const int m0 = blockIdx.x << 7, n0 = blockIdx.y << 7;
    const int wr = (w >> 1) << 6, wc = (w & 1) << 6;
    f32x4 acc[4][4] = {};

    // staging: wave w, instr i covers rows w*32+i*16 .. +16 (64B/row, 4 lanes/row)
    const ushort* ga0 = A  + (size_t)(m0 + (w << 5) + (l >> 2)) * K + ((l & 3) << 3);
    const ushort* ga1 = ga0 + (size_t)16 * K;
    const ushort* gb0 = Bw + (size_t)(n0 + (w << 5) + (l >> 2)) * K + ((l & 3) << 3);
    const ushort* gb1 = gb0 + (size_t)16 * K;
    ushort* la0 = As + (w << 10);
    ushort* la1 = As + (w << 10) + 512;
    ushort* lb0 = Bs + (w << 10);
    ushort* lb1 = Bs + (w << 10) + 512;

    const int fr_a = wr + (l & 15);
    const int fr_b = wc + (l & 15);
    const int fk   = (l >> 4) << 3;

    const int nk = K >> 5;
    for (int kt = 0; kt < nk; ++kt) {
        __syncthreads();
        gl_lds16(ga0, la0); gl_lds16(ga1, la1);
        gl_lds16(gb0, lb0); gl_lds16(gb1, lb1);
        ga0 += 32; ga1 += 32; gb0 += 32; gb1 += 32;
        __syncthreads();
        s16x8 af[4], bf[4];
        #pragma unroll
        for (int x = 0; x < 4; ++x) {
            af[x] = *(const s16x8*)&As[(fr_a + (x << 4)) * 32 + fk];
            bf[x] = *(const s16x8*)&Bs[(fr_b + (x << 4)) * 32 + fk];
        }
        #pragma unroll
        for (int x = 0; x < 4; ++x)
            #pragma unroll
            for (int y = 0; y < 4; ++y)
                acc[x][y] = __builtin_amdgcn_mfma_f32_16x16x32_bf16(
                    af[x], bf[y], acc[x][y], 0, 0, 0);
    }

    const int col0 = n0 + wc + (l & 15);
    const int row0 = m0 + wr + ((l >> 4) << 2);
    #pragma unroll
    for (int x = 0; x < 4; ++x) {
        #pragma unroll
        for (int y = 0; y < 4; ++y) {
            int col = col0 + (y << 4);
            if (col >= N) continue;
            float bv = bias ? bias[col] : 0.f;
            #pragma unroll
            for (int i = 0; i < 4; ++i) {
                int row = row0 + (x << 4) + i;
                float v = acc[x][y][i] + bv;
                if (fuse == 1) v = gelu_f(v);
                else if (fuse == 2) v += resid[(size_t)row * N + col];
                if (Cf) Cf[(size_t)row * N + col] = v;
                if (Cb) Cb[(size_t)row * N + col] = f2b(v);
            }
        }
    }
}

// ---------------- bf16 MFMA flash attention ----------------
// qkv bf16 [NTOK,1536]; out bf16 [NTOK,512]. 64 q-rows/block, 4 waves (16 rows each).
__global__ __launch_bounds__(256) void attn_mfma(
    const ushort* __restrict__ qkv, ushort* __restrict__ out)
{
    __shared__ ushort Ks[64 * 72];   // [m][d]   row-major, padded (144B rows)
    __shared__ ushort Vt[64 * 72];   // [d][m]   transposed
    __shared__ ushort Ps[64 * 72];   // [q][m]   P transpose-through (wave-private rows)
    const int tid = threadIdx.x;
    const int l = tid & 63, w = tid >> 6;
    const int bh = blockIdx.y, b = bh >> 3, h = bh & 7;
    const int q0 = blockIdx.x << 6;
    const ushort* base = qkv + (size_t)b * SEQ * 1536 + h * 64;

    // Q fragments register-resident: rows q0 + w*16 + (l&15)
    s16x8 qf[2];
    {
        const ushort* qrow = base + (size_t)(q0 + (w << 4) + (l & 15)) * 1536 + ((l >> 4) << 3);
        qf[0] = *(const s16x8*)qrow;
        qf[1] = *(const s16x8*)(qrow + 32);
    }
    f32x4 accO[4] = {};
    float m_run[4], l_run[4];
    #pragma unroll
    for (int i = 0; i < 4; ++i) { m_run[i] = -1e30f; l_run[i] = 0.f; }

    // staging geometry: thread covers row sr, 16 cols at sc
    const int sr = (w << 4) + (l >> 2), sc = (l & 3) << 4;
    const ushort* kbase = base + 512  + (size_t)sr * 1536 + sc;
    const ushort* vbase = base + 1024 + (size_t)sr * 1536 + sc;

    for (int kt = 0; kt < SEQ / 64; ++kt) {
        const size_t koff = (size_t)(kt << 6) * 1536;
        __syncthreads();
        {
            s16x8 k0 = *(const s16x8*)(kbase + koff);
            s16x8 k1 = *(const s16x8*)(kbase + koff + 8);
            *(s16x8*)&Ks[sr * 72 + sc]     = k0;
            *(s16x8*)&Ks[sr * 72 + sc + 8] = k1;
            s16x8 v0 = *(const s16x8*)(vbase + koff);
            s16x8 v1 = *(const s16x8*)(vbase + koff + 8);
            #pragma unroll
            for (int j = 0; j < 8; ++j) {
                Vt[(sc + j) * 72 + sr]     = (ushort)v0[j];
                Vt[(sc + 8 + j) * 72 + sr] = (ushort)v1[j];
            }
        }
        __syncthreads();

        // S = Q K^T   (16x64 per wave, 4 col-frags x 2 k-steps)
        f32x4 s[4] = {};
        #pragma unroll
        for (int ks = 0; ks < 2; ++ks)
            #pragma unroll
            for (int n = 0; n < 4; ++n) {
                s16x8 kf = *(const s16x8*)&Ks[((n << 4) + (l & 15)) * 72 + (ks << 5) + ((l >> 4) << 3)];
                s[n] = __builtin_amdgcn_mfma_f32_16x16x32_bf16(qf[ks], kf, s[n], 0, 0, 0);
            }
        #pragma unroll
        for (int n = 0; n < 4; ++n) s[n] *= 0.125f;   // 1/sqrt(64)

        // online softmax: lane holds rows 4*(l>>4)+i, cols n*16+(l&15)
        float p[4][4];
        #pragma unroll
        for (int i = 0; i < 4; ++i) {
            float mt = fmaxf(fmaxf(s[0][i], s[1][i]), fmaxf(s[2][i], s[3][i]));
            #pragma unroll
            for (int o = 1; o < 16; o <<= 1) mt = fmaxf(mt, __shfl_xor(mt, o));
            float mn = fmaxf(m_run[i], mt);
            float scf = __expf(m_run[i] - mn);
            float rs = 0.f;
            #pragma unroll
            for (int n = 0; n < 4; ++n) { p[n][i] = __expf(s[n][i] - mn); rs += p[n][i]; }
            #pragma unroll
            for (int o = 1; o < 16; o <<= 1) rs += __shfl_xor(rs, o);
            l_run[i] = l_run[i] * scf + rs;
            m_run[i] = mn;
            #pragma unroll
            for (int n = 0; n < 4; ++n) accO[n][i] *= scf;
        }
        // P -> LDS (bf16), wave-private rows
        const int prow = (w << 4) + ((l >> 4) << 2);
        #pragma unroll
        for (int n = 0; n < 4; ++n)
            #pragma unroll
            for (int i = 0; i < 4; ++i)
                Ps[(prow + i) * 72 + (n << 4) + (l & 15)] = f2b(p[n][i]);
        asm volatile("s_waitcnt lgkmcnt(0)" ::: "memory");
        __builtin_amdgcn_sched_barrier(0);

        // O += P @ V
        #pragma unroll
        for (int ks = 0; ks < 2; ++ks) {
            s16x8 pf = *(const s16x8*)&Ps[((w << 4) + (l & 15)) * 72 + (ks << 5) + ((l >> 4) << 3)];
            #pragma unroll
            for (int n = 0; n < 4; ++n) {
                s16x8 vf = *(const s16x8*)&Vt[((n << 4) + (l & 15)) * 72 + (ks << 5) + ((l >> 4) << 3)];
                accO[n] = __builtin_amdgcn_mfma_f32_16x16x32_bf16(pf, vf, accO[n], 0, 0, 0);
            }
        }
    }

    const int orow = q0 + (w << 4) + ((l >> 4) << 2);
    ushort* obase = out + (size_t)(b * SEQ) * 512 + h * 64 + (l & 15);
    #pragma unroll
    for (int i = 0; i < 4; ++i) {
        float inv = 1.0f / l_run[i];
        #pragma unroll
        for (int n = 0; n < 4; ++n)
            obase[(size_t)(orow + i) * 512 + (n << 4)] = f2b(accO[n][i] * inv);
    }
}

extern "C" void kernel_launch(void* const* d_in, const int* in_sizes, int n_in,
                              void* d_out, int out_size, void* d_ws, size_t ws_size,
                              hipStream_t stream) {
    const int*   x     = (const int*)  d_in[0];
    const float* embed = (const float*)d_in[1];
    const float* ep_w  = (const float*)d_in[2];
    const float* ep_b  = (const float*)d_in[3];
    const float* in_w  = (const float*)d_in[4];
    const float* in_b  = (const float*)d_in[5];
    const float* op_w  = (const float*)d_in[6];
    const float* op_b  = (const float*)d_in[7];
    const float* ln1_w = (const float*)d_in[8];
    const float* ln1_b = (const float*)d_in[9];
    const float* ln2_w = (const float*)d_in[10];
    const float* ln2_b = (const float*)d_in[11];
    const float* f1_w  = (const float*)d_in[12];
    const float* f1_b  = (const float*)d_in[13];
    const float* f2_w  = (const float*)d_in[14];
    const float* f2_b  = (const float*)d_in[15];
    const float* out_w = (const float*)d_in[16];
    float* out = (float*)d_out;

    // workspace layout (bytes)
    char* ws = (char*)d_ws;
    float*  h    = (float*) (ws + 0);           // 16,777,216
    ushort* g    = (ushort*)(ws + 16777216);    //  8,388,608  (LN out / attn out)
    ushort* big  = (ushort*)(ws + 25165824);    // 33,554,432  (qkv / ffn-mid, time-shared)
    ushort* qkvb = big;
    ushort* hb   = (ushort*)(ws + 58720256);    //  8,388,608  (bf16 final h)
    ushort* wq   = (ushort*)(ws + 67108864);    //  1,572,864
    ushort* wo   = (ushort*)(ws + 68681728);    //    524,288
    ushort* w1   = (ushort*)(ws + 69206016);    //  2,097,152
    ushort* w2   = (ushort*)(ws + 71303168);    //  2,097,152
    ushort* wv   = (ushort*)(ws + 73400320);    //    393,216  -> total ~70.4 MB

    hipMemsetAsync(wv, 0, (size_t)VPAD * 512 * 2, stream);
    cvt_bf16<<<(VOCAB * 512 / 4 + 255) / 256, 256, 0, stream>>>(out_w, wv, VOCAB * 512);

    embed_kernel<<<NTOK, 128, 0, stream>>>(x, embed, ep_w, ep_b, h);

    for (int l = 0; l < NLAYER; ++l) {
        cvt_bf16<<<768, 256, 0, stream>>>(in_w + (size_t)l * 786432, wq, 786432);
        cvt_bf16<<<256, 256, 0, stream>>>(op_w + (size_t)l * 262144, wo, 262144);
        cvt_bf16<<<1024, 256, 0, stream>>>(f1_w + (size_t)l * 1048576, w1, 1048576);
        cvt_bf16<<<1024, 256, 0, stream>>>(f2_w + (size_t)l * 1048576, w2, 1048576);

        ln_kernel<<<NTOK / 4, 256, 0, stream>>>(h, ln1_w + l * 512, ln1_b + l * 512, g);
        gemm_bf16<<<dim3(64, 12), 256, 0, stream>>>(g, wq, in_b + l * 1536, nullptr,
                                                    nullptr, qkvb, NTOK, 1536, 512, 0);
        attn_mfma<<<dim3(16, 64), 256, 0, stream>>>(qkvb, g);
        gemm_bf16<<<dim3(64, 4), 256, 0, stream>>>(g, wo, op_b + l * 512, h,
                                                   h, nullptr, NTOK, 512, 512, 2);
        ln_kernel<<<NTOK / 4, 256, 0, stream>>>(h, ln2_w + l * 512, ln2_b + l * 512, g);
        gemm_bf16<<<dim3(64, 16), 256, 0, stream>>>(g, w1, f1_b + l * 2048, nullptr,
                                                    nullptr, big, NTOK, 2048, 512, 1);
        gemm_bf16<<<dim3(64, 4), 256, 0, stream>>>(big, w2, f2_b + l * 512, h,
                                                   h, (l == NLAYER - 1) ? hb : nullptr,
                                                   NTOK, 512, 2048, 2);
    }

    gemm_bf16<<<dim3(64, 3), 256, 0, stream>>>(hb, wv, nullptr, nullptr,
                                               out, nullptr, NTOK, VOCAB, 512, 0);
}